// Round 1
// baseline (4018.002 us; speedup 1.0000x reference)
//
#include <hip/hip_runtime.h>
#include <math.h>

#define Nn 50000
#define Ee 1600000
#define Bb 512
#define EIN 129
#define TE 64

__device__ __forceinline__ float silu_f(float v) {
    return v / (1.f + __expf(-v));
}

// ---------------- init: h = emb[z] ----------------
__global__ void k_init_h(float* __restrict__ h, const int* __restrict__ z,
                         const float* __restrict__ emb) {
    int i = blockIdx.x * blockDim.x + threadIdx.x;
    if (i < Nn * 64) {
        int n = i >> 6, f = i & 63;
        h[i] = emb[z[n] * 64 + f];
    }
}

// ---------------- CSR build ----------------
__global__ void k_hist(const int* __restrict__ rows, int* __restrict__ deg) {
    int e = blockIdx.x * blockDim.x + threadIdx.x;
    if (e < Ee) atomicAdd(&deg[rows[e]], 1);
}

__global__ void k_scan(const int* __restrict__ deg, int* __restrict__ rp) {
    __shared__ int s[1024];
    __shared__ int carry_s;
    int t = threadIdx.x;
    if (t == 0) carry_s = 0;
    __syncthreads();
    for (int base = 0; base < Nn; base += 1024) {
        int v = (base + t < Nn) ? deg[base + t] : 0;
        s[t] = v;
        __syncthreads();
        for (int off = 1; off < 1024; off <<= 1) {
            int u = (t >= off) ? s[t - off] : 0;
            __syncthreads();
            s[t] += u;
            __syncthreads();
        }
        int carry = carry_s;
        if (base + t < Nn) rp[base + t] = carry + s[t] - v;
        int tot = s[1023];
        __syncthreads();
        if (t == 0) carry_s = carry + tot;
        __syncthreads();
    }
    if (t == 0) rp[Nn] = carry_s;
}

__global__ void k_scatter(const int* __restrict__ rows, const int* __restrict__ cols,
                          const int* __restrict__ rp, int* __restrict__ cur,
                          int* __restrict__ rows_s, int* __restrict__ cols_s) {
    int e = blockIdx.x * blockDim.x + threadIdx.x;
    if (e < Ee) {
        int r = rows[e];
        int p = atomicAdd(&cur[r], 1);
        int o = rp[r] + p;
        rows_s[o] = r;
        cols_s[o] = cols[e];
    }
}

// ---------------- edge kernel (per layer) ----------------
#define FMA16(ACC, EV, WV)                                         \
    ACC[0][0] = fmaf(EV.x, WV.x, ACC[0][0]);                       \
    ACC[0][1] = fmaf(EV.x, WV.y, ACC[0][1]);                       \
    ACC[0][2] = fmaf(EV.x, WV.z, ACC[0][2]);                       \
    ACC[0][3] = fmaf(EV.x, WV.w, ACC[0][3]);                       \
    ACC[1][0] = fmaf(EV.y, WV.x, ACC[1][0]);                       \
    ACC[1][1] = fmaf(EV.y, WV.y, ACC[1][1]);                       \
    ACC[1][2] = fmaf(EV.y, WV.z, ACC[1][2]);                       \
    ACC[1][3] = fmaf(EV.y, WV.w, ACC[1][3]);                       \
    ACC[2][0] = fmaf(EV.z, WV.x, ACC[2][0]);                       \
    ACC[2][1] = fmaf(EV.z, WV.y, ACC[2][1]);                       \
    ACC[2][2] = fmaf(EV.z, WV.z, ACC[2][2]);                       \
    ACC[2][3] = fmaf(EV.z, WV.w, ACC[2][3]);                       \
    ACC[3][0] = fmaf(EV.w, WV.x, ACC[3][0]);                       \
    ACC[3][1] = fmaf(EV.w, WV.y, ACC[3][1]);                       \
    ACC[3][2] = fmaf(EV.w, WV.z, ACC[3][2]);                       \
    ACC[3][3] = fmaf(EV.w, WV.w, ACC[3][3]);

__global__ __launch_bounds__(256) void k_edge(
    const int* __restrict__ rows_s, const int* __restrict__ cols_s,
    const float* __restrict__ h, const float* __restrict__ x,
    const float* __restrict__ w1, const float* __restrict__ b1v,
    const float* __restrict__ w2, const float* __restrict__ b2v,
    const float* __restrict__ cwv, const float* __restrict__ cbv,
    float* __restrict__ m_agg, float* __restrict__ x_acc) {
    __shared__ float eiT[EIN * 64];   // [k][e]; reused as mE[e][f] after GEMM1
    __shared__ float h1T[64 * 64];    // [k][e]
    __shared__ float relsm[64 * 4];
    __shared__ float coefs[64];
    __shared__ int srow[64];
    __shared__ int segs[65];
    __shared__ int segr[64];
    __shared__ int nseg_s;
    __shared__ float sb1[64], sb2[64], scw[64];
    float* mE = eiT;

    const int t = threadIdx.x;
    const int tx = t & 15, ty = t >> 4;
    const int f0 = tx * 4, e0 = ty * 4;
    if (t < 64) { sb1[t] = b1v[t]; sb2[t] = b2v[t]; scw[t] = cwv[t]; }
    const float cb0 = cbv[0];

    for (int tile = blockIdx.x; tile < Ee / TE; tile += gridDim.x) {
        const int base = tile * TE;
        __syncthreads();  // protect LDS reuse across iterations

        // phase 0: geometry (one edge per thread, wave 0)
        if (t < TE) {
            int r = rows_s[base + t], c = cols_s[base + t];
            srow[t] = r;
            float rx = x[r * 3 + 0] - x[c * 3 + 0];
            float ry = x[r * 3 + 1] - x[c * 3 + 1];
            float rz = x[r * 3 + 2] - x[c * 3 + 2];
            relsm[t * 4 + 0] = rx;
            relsm[t * 4 + 1] = ry;
            relsm[t * 4 + 2] = rz;
            eiT[128 * 64 + t] = fmaf(rx, rx, fmaf(ry, ry, rz * rz));
        }
        // gather h[row], h[col] -> eiT transposed
        {
            int e = t >> 2, part = t & 3;
            int r = rows_s[base + e], c = cols_s[base + e];
            const float4* hr = (const float4*)(h + (size_t)r * 64 + part * 16);
            const float4* hc = (const float4*)(h + (size_t)c * 64 + part * 16);
#pragma unroll
            for (int j = 0; j < 4; ++j) {
                float4 v = hr[j];
                int f = part * 16 + j * 4;
                eiT[(f + 0) * 64 + e] = v.x;
                eiT[(f + 1) * 64 + e] = v.y;
                eiT[(f + 2) * 64 + e] = v.z;
                eiT[(f + 3) * 64 + e] = v.w;
            }
#pragma unroll
            for (int j = 0; j < 4; ++j) {
                float4 v = hc[j];
                int f = 64 + part * 16 + j * 4;
                eiT[(f + 0) * 64 + e] = v.x;
                eiT[(f + 1) * 64 + e] = v.y;
                eiT[(f + 2) * 64 + e] = v.z;
                eiT[(f + 3) * 64 + e] = v.w;
            }
        }
        __syncthreads();

        // segment detection (wave 0, ballot)
        if (t < TE) {
            bool isst = (t == 0) || (srow[t] != srow[t - 1]);
            unsigned long long mask = __ballot(isst);
            if (isst) {
                int si = __popcll(mask & ((1ull << t) - 1ull));
                segs[si] = t;
                segr[si] = srow[t];
            }
            if (t == 0) {
                int ns = __popcll(mask);
                nseg_s = ns;
                segs[ns] = TE;
            }
        }

        // GEMM1: [64e x 129] @ [129 x 64f]
        float acc[4][4];
#pragma unroll
        for (int i = 0; i < 4; ++i)
#pragma unroll
            for (int j = 0; j < 4; ++j) acc[i][j] = sb1[f0 + j];
#pragma unroll 4
        for (int k = 0; k < EIN; ++k) {
            const float4 wv = *(const float4*)(w1 + (k << 6) + f0);
            const float4 ev = *(const float4*)(eiT + (k << 6) + e0);
            FMA16(acc, ev, wv)
        }
        // silu -> h1T (transposed)
#pragma unroll
        for (int j = 0; j < 4; ++j) {
            float4 sv;
            sv.x = silu_f(acc[0][j]);
            sv.y = silu_f(acc[1][j]);
            sv.z = silu_f(acc[2][j]);
            sv.w = silu_f(acc[3][j]);
            *(float4*)(h1T + (f0 + j) * 64 + e0) = sv;
        }
        __syncthreads();

        // GEMM2: [64e x 64] @ [64 x 64f]
        float a2[4][4];
#pragma unroll
        for (int i = 0; i < 4; ++i)
#pragma unroll
            for (int j = 0; j < 4; ++j) a2[i][j] = sb2[f0 + j];
#pragma unroll 4
        for (int k = 0; k < 64; ++k) {
            const float4 wv = *(const float4*)(w2 + (k << 6) + f0);
            const float4 ev = *(const float4*)(h1T + (k << 6) + e0);
            FMA16(a2, ev, wv)
        }
        // m = silu(a2); store mE[e][f]; coef partials
        float pcoef[4];
#pragma unroll
        for (int i = 0; i < 4; ++i) {
            float4 mv;
            mv.x = silu_f(a2[i][0]);
            mv.y = silu_f(a2[i][1]);
            mv.z = silu_f(a2[i][2]);
            mv.w = silu_f(a2[i][3]);
            *(float4*)(mE + (e0 + i) * 64 + f0) = mv;
            pcoef[i] = fmaf(mv.x, scw[f0 + 0],
                       fmaf(mv.y, scw[f0 + 1],
                       fmaf(mv.z, scw[f0 + 2], mv.w * scw[f0 + 3])));
        }
#pragma unroll
        for (int off = 1; off < 16; off <<= 1) {
#pragma unroll
            for (int i = 0; i < 4; ++i) pcoef[i] += __shfl_xor(pcoef[i], off);
        }
        if (tx == 0) {
#pragma unroll
            for (int i = 0; i < 4; ++i) coefs[e0 + i] = tanhf(pcoef[i] + cb0);
        }
        __syncthreads();

        // segmented aggregation
        {
            int f = t & 63, g = t >> 6;
            int ns = nseg_s;
            for (int s = g; s < ns; s += 4) {
                int st = segs[s], en = segs[s + 1];
                float sum = 0.f;
                for (int e = st; e < en; ++e) sum += mE[e * 64 + f];
                atomicAdd(m_agg + (size_t)segr[s] * 64 + f, sum);
            }
            if (t < 3 * ns) {
                int s = t / 3, c = t - s * 3;
                int st = segs[s], en = segs[s + 1];
                float sum = 0.f;
                for (int e = st; e < en; ++e) sum += relsm[e * 4 + c] * coefs[e];
                atomicAdd(x_acc + (size_t)segr[s] * 3 + c, sum);
            }
        }
    }
}

// ---------------- node kernel (per layer) ----------------
__global__ __launch_bounds__(256) void k_node(
    const float* __restrict__ m_agg, const float* __restrict__ x_acc,
    const float* __restrict__ w1, const float* __restrict__ b1v,
    const float* __restrict__ w2, const float* __restrict__ b2v,
    float* __restrict__ h, float* __restrict__ x) {
    __shared__ float inT[128 * 64];
    __shared__ float h1T[64 * 64];
    __shared__ float sb1[64], sb2[64];
    const int t = threadIdx.x;
    const int tx = t & 15, ty = t >> 4;
    const int f0 = tx * 4, e0 = ty * 4;
    if (t < 64) { sb1[t] = b1v[t]; sb2[t] = b2v[t]; }
    const int base = blockIdx.x * 64;
    {
        int nl = t >> 2, part = t & 3;
        int n = base + nl;
        if (n < Nn) {
            const float4* hr = (const float4*)(h + (size_t)n * 64 + part * 16);
            const float4* mr = (const float4*)(m_agg + (size_t)n * 64 + part * 16);
#pragma unroll
            for (int j = 0; j < 4; ++j) {
                float4 v = hr[j];
                int f = part * 16 + j * 4;
                inT[(f + 0) * 64 + nl] = v.x;
                inT[(f + 1) * 64 + nl] = v.y;
                inT[(f + 2) * 64 + nl] = v.z;
                inT[(f + 3) * 64 + nl] = v.w;
            }
#pragma unroll
            for (int j = 0; j < 4; ++j) {
                float4 v = mr[j];
                int f = 64 + part * 16 + j * 4;
                inT[(f + 0) * 64 + nl] = v.x;
                inT[(f + 1) * 64 + nl] = v.y;
                inT[(f + 2) * 64 + nl] = v.z;
                inT[(f + 3) * 64 + nl] = v.w;
            }
        } else {
#pragma unroll
            for (int j = 0; j < 4; ++j) {
                int f = part * 16 + j * 4;
#pragma unroll
                for (int i = 0; i < 4; ++i) {
                    inT[(f + i) * 64 + nl] = 0.f;
                    inT[(64 + f + i) * 64 + nl] = 0.f;
                }
            }
        }
    }
    __syncthreads();
    float acc[4][4];
#pragma unroll
    for (int i = 0; i < 4; ++i)
#pragma unroll
        for (int j = 0; j < 4; ++j) acc[i][j] = sb1[f0 + j];
#pragma unroll 4
    for (int k = 0; k < 128; ++k) {
        const float4 wv = *(const float4*)(w1 + (k << 6) + f0);
        const float4 ev = *(const float4*)(inT + (k << 6) + e0);
        FMA16(acc, ev, wv)
    }
#pragma unroll
    for (int j = 0; j < 4; ++j) {
        float4 sv;
        sv.x = silu_f(acc[0][j]);
        sv.y = silu_f(acc[1][j]);
        sv.z = silu_f(acc[2][j]);
        sv.w = silu_f(acc[3][j]);
        *(float4*)(h1T + (f0 + j) * 64 + e0) = sv;
    }
    __syncthreads();
    float a2[4][4];
#pragma unroll
    for (int i = 0; i < 4; ++i)
#pragma unroll
        for (int j = 0; j < 4; ++j) a2[i][j] = sb2[f0 + j];
#pragma unroll 4
    for (int k = 0; k < 64; ++k) {
        const float4 wv = *(const float4*)(w2 + (k << 6) + f0);
        const float4 ev = *(const float4*)(h1T + (k << 6) + e0);
        FMA16(a2, ev, wv)
    }
    // h += dh
#pragma unroll
    for (int i = 0; i < 4; ++i) {
        int n = base + e0 + i;
        if (n < Nn) {
            float4* hp = (float4*)(h + (size_t)n * 64 + f0);
            float4 old = *hp;
            old.x += a2[i][0];
            old.y += a2[i][1];
            old.z += a2[i][2];
            old.w += a2[i][3];
            *hp = old;
        }
    }
    // x += dx
    if (t < 64) {
        int n = base + t;
        if (n < Nn) {
#pragma unroll
            for (int c = 0; c < 3; ++c) x[n * 3 + c] += x_acc[n * 3 + c];
        }
    }
}

// ---------------- readout q ----------------
__global__ __launch_bounds__(256) void k_q(
    const float* __restrict__ h,
    const float* __restrict__ w1, const float* __restrict__ b1v,
    const float* __restrict__ w2, const float* __restrict__ b2v,
    float* __restrict__ q) {
    __shared__ float hT[64 * 64];
    __shared__ float sb1[64], sw2[64];
    const int t = threadIdx.x;
    const int tx = t & 15, ty = t >> 4;
    const int f0 = tx * 4, e0 = ty * 4;
    if (t < 64) { sb1[t] = b1v[t]; sw2[t] = w2[t]; }
    const float qb2 = b2v[0];
    const int base = blockIdx.x * 64;
    {
        int nl = t >> 2, part = t & 3;
        int n = base + nl;
        if (n < Nn) {
            const float4* hr = (const float4*)(h + (size_t)n * 64 + part * 16);
#pragma unroll
            for (int j = 0; j < 4; ++j) {
                float4 v = hr[j];
                int f = part * 16 + j * 4;
                hT[(f + 0) * 64 + nl] = v.x;
                hT[(f + 1) * 64 + nl] = v.y;
                hT[(f + 2) * 64 + nl] = v.z;
                hT[(f + 3) * 64 + nl] = v.w;
            }
        } else {
#pragma unroll
            for (int j = 0; j < 4; ++j) {
                int f = part * 16 + j * 4;
#pragma unroll
                for (int i = 0; i < 4; ++i) hT[(f + i) * 64 + nl] = 0.f;
            }
        }
    }
    __syncthreads();
    float acc[4][4];
#pragma unroll
    for (int i = 0; i < 4; ++i)
#pragma unroll
        for (int j = 0; j < 4; ++j) acc[i][j] = sb1[f0 + j];
#pragma unroll 4
    for (int k = 0; k < 64; ++k) {
        const float4 wv = *(const float4*)(w1 + (k << 6) + f0);
        const float4 ev = *(const float4*)(hT + (k << 6) + e0);
        FMA16(acc, ev, wv)
    }
    float p[4];
#pragma unroll
    for (int i = 0; i < 4; ++i) {
        p[i] = fmaf(silu_f(acc[i][0]), sw2[f0 + 0],
               fmaf(silu_f(acc[i][1]), sw2[f0 + 1],
               fmaf(silu_f(acc[i][2]), sw2[f0 + 2],
                    silu_f(acc[i][3]) * sw2[f0 + 3])));
    }
#pragma unroll
    for (int off = 1; off < 16; off <<= 1) {
#pragma unroll
        for (int i = 0; i < 4; ++i) p[i] += __shfl_xor(p[i], off);
    }
    if (tx == 0) {
#pragma unroll
        for (int i = 0; i < 4; ++i) {
            int n = base + e0 + i;
            if (n < Nn) q[n] = p[i] + qb2;
        }
    }
}

// ---------------- batch stats & dipole ----------------
__global__ void k_batch(const int* __restrict__ batch, const float* __restrict__ x,
                        float* __restrict__ cnt, float* __restrict__ xs) {
    int n = blockIdx.x * blockDim.x + threadIdx.x;
    if (n < Nn) {
        int b = batch[n];
        atomicAdd(&cnt[b], 1.f);
        atomicAdd(&xs[b * 3 + 0], x[n * 3 + 0]);
        atomicAdd(&xs[b * 3 + 1], x[n * 3 + 1]);
        atomicAdd(&xs[b * 3 + 2], x[n * 3 + 2]);
    }
}

__global__ void k_mu(const int* __restrict__ batch, const float* __restrict__ x,
                     const float* __restrict__ q, const float* __restrict__ cnt,
                     const float* __restrict__ xs, float* __restrict__ out) {
    int n = blockIdx.x * blockDim.x + threadIdx.x;
    if (n < Nn) {
        int b = batch[n];
        float cc = fmaxf(cnt[b], 1.f);
        float qn = q[n];
#pragma unroll
        for (int c = 0; c < 3; ++c) {
            float xr = x[n * 3 + c] - xs[b * 3 + c] / cc;
            atomicAdd(&out[b * 3 + c], qn * xr);
        }
    }
}

// ---------------- launch ----------------
extern "C" void kernel_launch(void* const* d_in, const int* in_sizes, int n_in,
                              void* d_out, int out_size, void* d_ws, size_t ws_size,
                              hipStream_t stream) {
    const int* z = (const int*)d_in[0];
    const float* pos = (const float*)d_in[1];
    const int* ei0 = (const int*)d_in[2];
    const int* ei1 = ei0 + Ee;
    const int* batch = (const int*)d_in[3];
    const float* emb = (const float*)d_in[4];
    const float* eW1 = (const float*)d_in[5];
    const float* eb1 = (const float*)d_in[6];
    const float* eW2 = (const float*)d_in[7];
    const float* eb2 = (const float*)d_in[8];
    const float* cW = (const float*)d_in[9];
    const float* cb = (const float*)d_in[10];
    const float* nW1 = (const float*)d_in[11];
    const float* nb1 = (const float*)d_in[12];
    const float* nW2 = (const float*)d_in[13];
    const float* nb2 = (const float*)d_in[14];
    const float* qW1 = (const float*)d_in[15];
    const float* qb1 = (const float*)d_in[16];
    const float* qW2 = (const float*)d_in[17];
    const float* qb2 = (const float*)d_in[18];

    char* ws = (char*)d_ws;
    size_t o = 0;
    auto alloc = [&](size_t bytes) {
        size_t r = o;
        o = (o + bytes + 255) & ~(size_t)255;
        return r;
    };
    float* h = (float*)(ws + alloc((size_t)Nn * 64 * 4));
    float* xp = (float*)(ws + alloc((size_t)Nn * 3 * 4));
    float* magg = (float*)(ws + alloc((size_t)Nn * 64 * 4));
    float* xacc = (float*)(ws + alloc((size_t)Nn * 3 * 4));
    float* qv = (float*)(ws + alloc((size_t)Nn * 4));
    int* deg = (int*)(ws + alloc((size_t)Nn * 4));
    int* rp = (int*)(ws + alloc((size_t)(Nn + 1) * 4));
    int* cur = (int*)(ws + alloc((size_t)Nn * 4));
    int* rows_s = (int*)(ws + alloc((size_t)Ee * 4));
    int* cols_s = (int*)(ws + alloc((size_t)Ee * 4));
    float* cnt = (float*)(ws + alloc((size_t)Bb * 4));
    float* xs = (float*)(ws + alloc((size_t)Bb * 3 * 4));

    hipMemsetAsync(deg, 0, (size_t)Nn * 4, stream);
    hipMemsetAsync(cur, 0, (size_t)Nn * 4, stream);
    hipMemsetAsync(cnt, 0, (size_t)Bb * 4, stream);
    hipMemsetAsync(xs, 0, (size_t)Bb * 3 * 4, stream);
    hipMemsetAsync(d_out, 0, (size_t)out_size * 4, stream);

    k_init_h<<<(Nn * 64 + 255) / 256, 256, 0, stream>>>(h, z, emb);
    hipMemcpyAsync(xp, pos, (size_t)Nn * 3 * 4, hipMemcpyDeviceToDevice, stream);
    k_hist<<<(Ee + 255) / 256, 256, 0, stream>>>(ei0, deg);
    k_scan<<<1, 1024, 0, stream>>>(deg, rp);
    k_scatter<<<(Ee + 255) / 256, 256, 0, stream>>>(ei0, ei1, rp, cur, rows_s, cols_s);

    for (int l = 0; l < 4; ++l) {
        hipMemsetAsync(magg, 0, (size_t)Nn * 64 * 4, stream);
        hipMemsetAsync(xacc, 0, (size_t)Nn * 3 * 4, stream);
        k_edge<<<2048, 256, 0, stream>>>(rows_s, cols_s, h, xp,
                                         eW1 + (size_t)l * EIN * 64, eb1 + l * 64,
                                         eW2 + (size_t)l * 4096, eb2 + l * 64,
                                         cW + l * 64, cb + l, magg, xacc);
        k_node<<<(Nn + 63) / 64, 256, 0, stream>>>(magg, xacc,
                                                   nW1 + (size_t)l * 8192, nb1 + l * 64,
                                                   nW2 + (size_t)l * 4096, nb2 + l * 64,
                                                   h, xp);
    }
    k_q<<<(Nn + 63) / 64, 256, 0, stream>>>(h, qW1, qb1, qW2, qb2, qv);
    k_batch<<<(Nn + 255) / 256, 256, 0, stream>>>(batch, xp, cnt, xs);
    k_mu<<<(Nn + 255) / 256, 256, 0, stream>>>(batch, xp, qv, cnt, xs, (float*)d_out);
}

// Round 3
// 1804.174 us; speedup vs baseline: 2.2271x; 2.2271x over previous
//
#include <hip/hip_runtime.h>
#include <math.h>

#define Nn 50000
#define Ee 1600000
#define Bb 512
#define TE 64

typedef __bf16 bf16;
typedef __bf16 bf16x8 __attribute__((ext_vector_type(8)));
typedef __bf16 bf16x4 __attribute__((ext_vector_type(4)));
typedef float f32x4 __attribute__((ext_vector_type(4)));

__device__ __forceinline__ float silu_f(float v) {
    return v / (1.f + __expf(-v));
}
__device__ __forceinline__ int pack2bf(float a, float b) {
    unsigned short ua = __builtin_bit_cast(unsigned short, (bf16)a);
    unsigned short ub = __builtin_bit_cast(unsigned short, (bf16)b);
    return (int)ua | ((int)ub << 16);
}

// ---------------- init: h = emb[z] (fp32 + bf16 mirror) ----------------
__global__ void k_init_h(float* __restrict__ h, bf16* __restrict__ hb,
                         const int* __restrict__ z, const float* __restrict__ emb) {
    int i = blockIdx.x * blockDim.x + threadIdx.x;
    if (i < Nn * 64) {
        int n = i >> 6, f = i & 63;
        float v = emb[z[n] * 64 + f];
        h[i] = v;
        hb[i] = (bf16)v;
    }
}

// ---------------- weight packing into MFMA A-fragment order ----------------
// pw1[l][((kc*4+T)*64 + lane)*8 + j] = bf16(W1[l][kc*32 + (lane>>4)*8 + j][T*16 + (lane&15)])
__global__ void k_pack(const float* __restrict__ eW1, const float* __restrict__ eW2,
                       bf16* __restrict__ pw1, bf16* __restrict__ pw2) {
    int tid = blockIdx.x * blockDim.x + threadIdx.x;
    if (tid < 4 * 8192) {
        int ll = tid >> 13, rem = tid & 8191;
        int j = rem & 7, lane = (rem >> 3) & 63, gT = rem >> 9;
        int kc = gT >> 2, T = gT & 3;
        int k = kc * 32 + (lane >> 4) * 8 + j;
        int n = T * 16 + (lane & 15);
        pw1[tid] = (bf16)eW1[(size_t)ll * 129 * 64 + k * 64 + n];
    } else if (tid < 4 * 8192 + 4 * 4096) {
        int idx = tid - 4 * 8192;
        int ll = idx >> 12, rem = idx & 4095;
        int j = rem & 7, lane = (rem >> 3) & 63, gT = rem >> 9;
        int kc = gT >> 2, T = gT & 3;
        int k = kc * 32 + (lane >> 4) * 8 + j;
        int n = T * 16 + (lane & 15);
        pw2[idx] = (bf16)eW2[(size_t)ll * 4096 + k * 64 + n];
    }
}

// ---------------- CSR build ----------------
__global__ void k_hist(const int* __restrict__ rows, int* __restrict__ deg) {
    int e = blockIdx.x * blockDim.x + threadIdx.x;
    if (e < Ee) atomicAdd(&deg[rows[e]], 1);
}

__global__ void k_scan(const int* __restrict__ deg, int* __restrict__ rp) {
    __shared__ int s[1024];
    __shared__ int carry_s;
    int t = threadIdx.x;
    if (t == 0) carry_s = 0;
    __syncthreads();
    for (int base = 0; base < Nn; base += 1024) {
        int v = (base + t < Nn) ? deg[base + t] : 0;
        s[t] = v;
        __syncthreads();
        for (int off = 1; off < 1024; off <<= 1) {
            int u = (t >= off) ? s[t - off] : 0;
            __syncthreads();
            s[t] += u;
            __syncthreads();
        }
        int carry = carry_s;
        if (base + t < Nn) rp[base + t] = carry + s[t] - v;
        int tot = s[1023];
        __syncthreads();
        if (t == 0) carry_s = carry + tot;
        __syncthreads();
    }
    if (t == 0) rp[Nn] = carry_s;
}

__global__ void k_scatter(const int* __restrict__ rows, const int* __restrict__ cols,
                          const int* __restrict__ rp, int* __restrict__ cur,
                          int* __restrict__ rows_s, int* __restrict__ cols_s) {
    int e = blockIdx.x * blockDim.x + threadIdx.x;
    if (e < Ee) {
        int r = rows[e];
        int p = atomicAdd(&cur[r], 1);
        int o = rp[r] + p;
        rows_s[o] = r;
        cols_s[o] = cols[e];
    }
}

// ---------------- edge kernel (MFMA, per layer) ----------------
// Per wave: 16 edges (cols). GEMM1: D1T[f][e] = sum_k W1[k][f]*ei[e][k] via
// mfma(A=W1^T frag, B=ei^T frag). dist2 enters as fp32 rank-1. GEMM2 via
// register-shuffle handoff (C-layout -> B-operand layout).
__global__ __launch_bounds__(256, 2) void k_edge(
    const int* __restrict__ rows_s, const int* __restrict__ cols_s,
    const bf16* __restrict__ hb, const float* __restrict__ x,
    const bf16* __restrict__ pw1l, const bf16* __restrict__ pw2l,
    const float* __restrict__ w1f32,
    const float* __restrict__ b1v, const float* __restrict__ b2v,
    const float* __restrict__ cwv, const float* __restrict__ cbv,
    float* __restrict__ m_agg, float* __restrict__ x_acc) {
    __shared__ __align__(16) bf16 hcatB[16 * 64 * 8];  // [kblock][edge][8]
    __shared__ float mE[64 * 65];                      // [n][e], stride 65
    __shared__ float relsm[64 * 4];
    __shared__ float dist2s[64];
    __shared__ float coefs[64];
    __shared__ int srow[64];
    __shared__ int segs[65];
    __shared__ int segr[64];
    __shared__ int nseg_s;

    const int t = threadIdx.x;
    const int l = t & 63;
    const int w = t >> 6;
    const int q = l >> 4;
    const int nl = l & 15;

    // weight fragments (constant over tiles)
    bf16x8 w1f[4][4];
#pragma unroll
    for (int kc = 0; kc < 4; ++kc)
#pragma unroll
        for (int T = 0; T < 4; ++T)
            w1f[kc][T] = *(const bf16x8*)(pw1l + (((kc * 4 + T) * 64 + l) << 3));
    bf16x8 w2f[2][4];
#pragma unroll
    for (int c = 0; c < 2; ++c)
#pragma unroll
        for (int T = 0; T < 4; ++T)
            w2f[c][T] = *(const bf16x8*)(pw2l + (((c * 4 + T) * 64 + l) << 3));
    float b1c[16], w128c[16], b2c[16], cWc[16];
#pragma unroll
    for (int T = 0; T < 4; ++T)
#pragma unroll
        for (int r = 0; r < 4; ++r) {
            int f = T * 16 + 4 * q + r;
            b1c[T * 4 + r] = b1v[f];
            w128c[T * 4 + r] = w1f32[128 * 64 + f];
            b2c[T * 4 + r] = b2v[f];
            cWc[T * 4 + r] = cwv[f];
        }
    const float cb0 = cbv[0];
    const int qh = q >> 1;
    const int qb = 2 * (q & 1);

    for (int tile = blockIdx.x; tile < Ee / TE; tile += gridDim.x) {
        const int base = tile * TE;
        __syncthreads();  // protect LDS reuse across iterations

        if (t < TE) {
            int r = rows_s[base + t], c = cols_s[base + t];
            srow[t] = r;
            float rx = x[r * 3 + 0] - x[c * 3 + 0];
            float ry = x[r * 3 + 1] - x[c * 3 + 1];
            float rz = x[r * 3 + 2] - x[c * 3 + 2];
            relsm[t * 4 + 0] = rx;
            relsm[t * 4 + 1] = ry;
            relsm[t * 4 + 2] = rz;
            dist2s[t] = fmaf(rx, rx, fmaf(ry, ry, rz * rz));
        }
        {
            int ge = t >> 2, part = t & 3;
            int r = rows_s[base + ge], c = cols_s[base + ge];
            const bf16* hr = hb + ((size_t)r << 6) + part * 16;
            const bf16* hc = hb + ((size_t)c << 6) + part * 16;
            *(bf16x8*)&hcatB[(((part * 2 + 0) * 64) + ge) << 3] = *(const bf16x8*)(hr);
            *(bf16x8*)&hcatB[(((part * 2 + 1) * 64) + ge) << 3] = *(const bf16x8*)(hr + 8);
            *(bf16x8*)&hcatB[(((8 + part * 2 + 0) * 64) + ge) << 3] = *(const bf16x8*)(hc);
            *(bf16x8*)&hcatB[(((8 + part * 2 + 1) * 64) + ge) << 3] = *(const bf16x8*)(hc + 8);
        }
        __syncthreads();

        if (t < TE) {
            bool isst = (t == 0) || (srow[t] != srow[t - 1]);
            unsigned long long mask = __ballot(isst);
            if (isst) {
                int si = __popcll(mask & ((1ull << t) - 1ull));
                segs[si] = t;
                segr[si] = srow[t];
            }
            if (t == 0) {
                int ns = __popcll(mask);
                nseg_s = ns;
                segs[ns] = TE;
            }
        }

        // GEMM1: 16 MFMAs
        f32x4 a1[4];
#pragma unroll
        for (int T = 0; T < 4; ++T) a1[T] = (f32x4){0.f, 0.f, 0.f, 0.f};
#pragma unroll
        for (int kc = 0; kc < 4; ++kc) {
            bf16x8 bfrag = *(const bf16x8*)&hcatB[(((kc * 4 + q) * 64) + w * 16 + nl) << 3];
#pragma unroll
            for (int T = 0; T < 4; ++T)
                a1[T] = __builtin_amdgcn_mfma_f32_16x16x32_bf16(w1f[kc][T], bfrag, a1[T], 0, 0, 0);
        }
        // epilogue1: bias + fp32 dist2 rank-1 + silu, pack bf16 pairs
        float d2 = dist2s[w * 16 + nl];
        int pk[4][2];
#pragma unroll
        for (int T = 0; T < 4; ++T) {
            float h0 = silu_f(a1[T][0] + b1c[T * 4 + 0] + w128c[T * 4 + 0] * d2);
            float h1 = silu_f(a1[T][1] + b1c[T * 4 + 1] + w128c[T * 4 + 1] * d2);
            float h2 = silu_f(a1[T][2] + b1c[T * 4 + 2] + w128c[T * 4 + 2] * d2);
            float h3 = silu_f(a1[T][3] + b1c[T * 4 + 3] + w128c[T * 4 + 3] * d2);
            pk[T][0] = pack2bf(h0, h1);
            pk[T][1] = pack2bf(h2, h3);
        }
        // GEMM2: register-shuffle B-frags, 8 MFMAs
        f32x4 a2[4];
#pragma unroll
        for (int T = 0; T < 4; ++T) a2[T] = (f32x4){0.f, 0.f, 0.f, 0.f};
#pragma unroll
        for (int c = 0; c < 2; ++c) {
            union { int i[4]; bf16x8 v; } bu;
#pragma unroll
            for (int d = 0; d < 4; ++d) {
                int src = (qb + (d >> 1)) * 16 + nl;
                int t0 = __shfl(pk[2 * c][d & 1], src);
                int t1 = __shfl(pk[2 * c + 1][d & 1], src);
                bu.i[d] = qh ? t1 : t0;
            }
#pragma unroll
            for (int T = 0; T < 4; ++T)
                a2[T] = __builtin_amdgcn_mfma_f32_16x16x32_bf16(w2f[c][T], bu.v, a2[T], 0, 0, 0);
        }
        // epilogue2: bias + silu -> mE; coef dot in fp32
        float pc = 0.f;
#pragma unroll
        for (int T = 0; T < 4; ++T)
#pragma unroll
            for (int r = 0; r < 4; ++r) {
                float mv = silu_f(a2[T][r] + b2c[T * 4 + r]);
                mE[(T * 16 + 4 * q + r) * 65 + w * 16 + nl] = mv;
                pc += mv * cWc[T * 4 + r];
            }
        pc += __shfl_xor(pc, 16);
        pc += __shfl_xor(pc, 32);
        if (q == 0) coefs[w * 16 + nl] = tanhf(pc + cb0);
        __syncthreads();

        // segmented aggregation
        {
            int g = t >> 6, n = t & 63;
            int ns = nseg_s;
            for (int s = g; s < ns; s += 4) {
                int st = segs[s], en = segs[s + 1];
                float sum = 0.f;
                for (int e = st; e < en; ++e) sum += mE[n * 65 + e];
                atomicAdd(m_agg + (size_t)segr[s] * 64 + n, sum);
            }
            if (t < 3 * ns) {
                int s = t / 3, cc = t - s * 3;
                int st = segs[s], en = segs[s + 1];
                float sum = 0.f;
                for (int e = st; e < en; ++e) sum += relsm[e * 4 + cc] * coefs[e];
                atomicAdd(x_acc + (size_t)segr[s] * 3 + cc, sum);
            }
        }
    }
}

// ---------------- node kernel (fp32, per layer) ----------------
#define FMA16(ACC, EV, WV)                                         \
    ACC[0][0] = fmaf(EV.x, WV.x, ACC[0][0]);                       \
    ACC[0][1] = fmaf(EV.x, WV.y, ACC[0][1]);                       \
    ACC[0][2] = fmaf(EV.x, WV.z, ACC[0][2]);                       \
    ACC[0][3] = fmaf(EV.x, WV.w, ACC[0][3]);                       \
    ACC[1][0] = fmaf(EV.y, WV.x, ACC[1][0]);                       \
    ACC[1][1] = fmaf(EV.y, WV.y, ACC[1][1]);                       \
    ACC[1][2] = fmaf(EV.y, WV.z, ACC[1][2]);                       \
    ACC[1][3] = fmaf(EV.y, WV.w, ACC[1][3]);                       \
    ACC[2][0] = fmaf(EV.z, WV.x, ACC[2][0]);                       \
    ACC[2][1] = fmaf(EV.z, WV.y, ACC[2][1]);                       \
    ACC[2][2] = fmaf(EV.z, WV.z, ACC[2][2]);                       \
    ACC[2][3] = fmaf(EV.z, WV.w, ACC[2][3]);                       \
    ACC[3][0] = fmaf(EV.w, WV.x, ACC[3][0]);                       \
    ACC[3][1] = fmaf(EV.w, WV.y, ACC[3][1]);                       \
    ACC[3][2] = fmaf(EV.w, WV.z, ACC[3][2]);                       \
    ACC[3][3] = fmaf(EV.w, WV.w, ACC[3][3]);

__global__ __launch_bounds__(256) void k_node(
    const float* __restrict__ m_agg, const float* __restrict__ x_acc,
    const float* __restrict__ w1, const float* __restrict__ b1v,
    const float* __restrict__ w2, const float* __restrict__ b2v,
    float* __restrict__ h, bf16* __restrict__ hb, float* __restrict__ x) {
    __shared__ float inT[128 * 64];
    __shared__ float h1T[64 * 64];
    __shared__ float sb1[64], sb2[64];
    const int t = threadIdx.x;
    const int tx = t & 15, ty = t >> 4;
    const int f0 = tx * 4, e0 = ty * 4;
    if (t < 64) { sb1[t] = b1v[t]; sb2[t] = b2v[t]; }
    const int base = blockIdx.x * 64;
    {
        int nl = t >> 2, part = t & 3;
        int n = base + nl;
        if (n < Nn) {
            const float4* hr = (const float4*)(h + (size_t)n * 64 + part * 16);
            const float4* mr = (const float4*)(m_agg + (size_t)n * 64 + part * 16);
#pragma unroll
            for (int j = 0; j < 4; ++j) {
                float4 v = hr[j];
                int f = part * 16 + j * 4;
                inT[(f + 0) * 64 + nl] = v.x;
                inT[(f + 1) * 64 + nl] = v.y;
                inT[(f + 2) * 64 + nl] = v.z;
                inT[(f + 3) * 64 + nl] = v.w;
            }
#pragma unroll
            for (int j = 0; j < 4; ++j) {
                float4 v = mr[j];
                int f = 64 + part * 16 + j * 4;
                inT[(f + 0) * 64 + nl] = v.x;
                inT[(f + 1) * 64 + nl] = v.y;
                inT[(f + 2) * 64 + nl] = v.z;
                inT[(f + 3) * 64 + nl] = v.w;
            }
        } else {
#pragma unroll
            for (int j = 0; j < 4; ++j) {
                int f = part * 16 + j * 4;
#pragma unroll
                for (int i = 0; i < 4; ++i) {
                    inT[(f + i) * 64 + nl] = 0.f;
                    inT[(64 + f + i) * 64 + nl] = 0.f;
                }
            }
        }
    }
    __syncthreads();
    float acc[4][4];
#pragma unroll
    for (int i = 0; i < 4; ++i)
#pragma unroll
        for (int j = 0; j < 4; ++j) acc[i][j] = sb1[f0 + j];
#pragma unroll 4
    for (int k = 0; k < 128; ++k) {
        const float4 wv = *(const float4*)(w1 + (k << 6) + f0);
        const float4 ev = *(const float4*)(inT + (k << 6) + e0);
        FMA16(acc, ev, wv)
    }
#pragma unroll
    for (int j = 0; j < 4; ++j) {
        float4 sv;
        sv.x = silu_f(acc[0][j]);
        sv.y = silu_f(acc[1][j]);
        sv.z = silu_f(acc[2][j]);
        sv.w = silu_f(acc[3][j]);
        *(float4*)(h1T + (f0 + j) * 64 + e0) = sv;
    }
    __syncthreads();
    float a2[4][4];
#pragma unroll
    for (int i = 0; i < 4; ++i)
#pragma unroll
        for (int j = 0; j < 4; ++j) a2[i][j] = sb2[f0 + j];
#pragma unroll 4
    for (int k = 0; k < 64; ++k) {
        const float4 wv = *(const float4*)(w2 + (k << 6) + f0);
        const float4 ev = *(const float4*)(h1T + (k << 6) + e0);
        FMA16(a2, ev, wv)
    }
#pragma unroll
    for (int i = 0; i < 4; ++i) {
        int n = base + e0 + i;
        if (n < Nn) {
            float4* hp = (float4*)(h + (size_t)n * 64 + f0);
            float4 old = *hp;
            old.x += a2[i][0];
            old.y += a2[i][1];
            old.z += a2[i][2];
            old.w += a2[i][3];
            *hp = old;
            bf16x4 hv = {(bf16)old.x, (bf16)old.y, (bf16)old.z, (bf16)old.w};
            *(bf16x4*)(hb + (size_t)n * 64 + f0) = hv;
        }
    }
    if (t < 64) {
        int n = base + t;
        if (n < Nn) {
#pragma unroll
            for (int c = 0; c < 3; ++c) x[n * 3 + c] += x_acc[n * 3 + c];
        }
    }
}

// ---------------- readout q ----------------
__global__ __launch_bounds__(256) void k_q(
    const float* __restrict__ h,
    const float* __restrict__ w1, const float* __restrict__ b1v,
    const float* __restrict__ w2, const float* __restrict__ b2v,
    float* __restrict__ q) {
    __shared__ float hT[64 * 64];
    __shared__ float sb1[64], sw2[64];
    const int t = threadIdx.x;
    const int tx = t & 15, ty = t >> 4;
    const int f0 = tx * 4, e0 = ty * 4;
    if (t < 64) { sb1[t] = b1v[t]; sw2[t] = w2[t]; }
    const float qb2 = b2v[0];
    const int base = blockIdx.x * 64;
    {
        int nl = t >> 2, part = t & 3;
        int n = base + nl;
        if (n < Nn) {
            const float4* hr = (const float4*)(h + (size_t)n * 64 + part * 16);
#pragma unroll
            for (int j = 0; j < 4; ++j) {
                float4 v = hr[j];
                int f = part * 16 + j * 4;
                hT[(f + 0) * 64 + nl] = v.x;
                hT[(f + 1) * 64 + nl] = v.y;
                hT[(f + 2) * 64 + nl] = v.z;
                hT[(f + 3) * 64 + nl] = v.w;
            }
        } else {
#pragma unroll
            for (int j = 0; j < 4; ++j) {
                int f = part * 16 + j * 4;
#pragma unroll
                for (int i = 0; i < 4; ++i) hT[(f + i) * 64 + nl] = 0.f;
            }
        }
    }
    __syncthreads();
    float acc[4][4];
#pragma unroll
    for (int i = 0; i < 4; ++i)
#pragma unroll
        for (int j = 0; j < 4; ++j) acc[i][j] = sb1[f0 + j];
#pragma unroll 4
    for (int k = 0; k < 64; ++k) {
        const float4 wv = *(const float4*)(w1 + (k << 6) + f0);
        const float4 ev = *(const float4*)(hT + (k << 6) + e0);
        FMA16(acc, ev, wv)
    }
    float p[4];
#pragma unroll
    for (int i = 0; i < 4; ++i) {
        p[i] = fmaf(silu_f(acc[i][0]), sw2[f0 + 0],
               fmaf(silu_f(acc[i][1]), sw2[f0 + 1],
               fmaf(silu_f(acc[i][2]), sw2[f0 + 2],
                    silu_f(acc[i][3]) * sw2[f0 + 3])));
    }
#pragma unroll
    for (int off = 1; off < 16; off <<= 1) {
#pragma unroll
        for (int i = 0; i < 4; ++i) p[i] += __shfl_xor(p[i], off);
    }
    if (tx == 0) {
#pragma unroll
        for (int i = 0; i < 4; ++i) {
            int n = base + e0 + i;
            if (n < Nn) q[n] = p[i] + qb2;
        }
    }
}

// ---------------- batch stats & dipole ----------------
__global__ void k_batch(const int* __restrict__ batch, const float* __restrict__ x,
                        float* __restrict__ cnt, float* __restrict__ xs) {
    int n = blockIdx.x * blockDim.x + threadIdx.x;
    if (n < Nn) {
        int b = batch[n];
        atomicAdd(&cnt[b], 1.f);
        atomicAdd(&xs[b * 3 + 0], x[n * 3 + 0]);
        atomicAdd(&xs[b * 3 + 1], x[n * 3 + 1]);
        atomicAdd(&xs[b * 3 + 2], x[n * 3 + 2]);
    }
}

__global__ void k_mu(const int* __restrict__ batch, const float* __restrict__ x,
                     const float* __restrict__ q, const float* __restrict__ cnt,
                     const float* __restrict__ xs, float* __restrict__ out) {
    int n = blockIdx.x * blockDim.x + threadIdx.x;
    if (n < Nn) {
        int b = batch[n];
        float cc = fmaxf(cnt[b], 1.f);
        float qn = q[n];
#pragma unroll
        for (int c = 0; c < 3; ++c) {
            float xr = x[n * 3 + c] - xs[b * 3 + c] / cc;
            atomicAdd(&out[b * 3 + c], qn * xr);
        }
    }
}

// ---------------- launch ----------------
extern "C" void kernel_launch(void* const* d_in, const int* in_sizes, int n_in,
                              void* d_out, int out_size, void* d_ws, size_t ws_size,
                              hipStream_t stream) {
    const int* z = (const int*)d_in[0];
    const float* pos = (const float*)d_in[1];
    const int* ei0 = (const int*)d_in[2];
    const int* ei1 = ei0 + Ee;
    const int* batch = (const int*)d_in[3];
    const float* emb = (const float*)d_in[4];
    const float* eW1 = (const float*)d_in[5];
    const float* eb1 = (const float*)d_in[6];
    const float* eW2 = (const float*)d_in[7];
    const float* eb2 = (const float*)d_in[8];
    const float* cW = (const float*)d_in[9];
    const float* cb = (const float*)d_in[10];
    const float* nW1 = (const float*)d_in[11];
    const float* nb1 = (const float*)d_in[12];
    const float* nW2 = (const float*)d_in[13];
    const float* nb2 = (const float*)d_in[14];
    const float* qW1 = (const float*)d_in[15];
    const float* qb1 = (const float*)d_in[16];
    const float* qW2 = (const float*)d_in[17];
    const float* qb2 = (const float*)d_in[18];

    char* ws = (char*)d_ws;
    size_t o = 0;
    auto alloc = [&](size_t bytes) {
        size_t r = o;
        o = (o + bytes + 255) & ~(size_t)255;
        return r;
    };
    float* h = (float*)(ws + alloc((size_t)Nn * 64 * 4));
    float* xp = (float*)(ws + alloc((size_t)Nn * 3 * 4));
    float* magg = (float*)(ws + alloc((size_t)Nn * 64 * 4));
    float* xacc = (float*)(ws + alloc((size_t)Nn * 3 * 4));
    float* qv = (float*)(ws + alloc((size_t)Nn * 4));
    int* deg = (int*)(ws + alloc((size_t)Nn * 4));
    int* rp = (int*)(ws + alloc((size_t)(Nn + 1) * 4));
    int* cur = (int*)(ws + alloc((size_t)Nn * 4));
    int* rows_s = (int*)(ws + alloc((size_t)Ee * 4));
    int* cols_s = (int*)(ws + alloc((size_t)Ee * 4));
    float* cnt = (float*)(ws + alloc((size_t)Bb * 4));
    float* xs = (float*)(ws + alloc((size_t)Bb * 3 * 4));
    bf16* hbm = (bf16*)(ws + alloc((size_t)Nn * 64 * 2));
    bf16* pw1 = (bf16*)(ws + alloc((size_t)4 * 8192 * 2));
    bf16* pw2 = (bf16*)(ws + alloc((size_t)4 * 4096 * 2));

    hipMemsetAsync(deg, 0, (size_t)Nn * 4, stream);
    hipMemsetAsync(cur, 0, (size_t)Nn * 4, stream);
    hipMemsetAsync(cnt, 0, (size_t)Bb * 4, stream);
    hipMemsetAsync(xs, 0, (size_t)Bb * 3 * 4, stream);
    hipMemsetAsync(d_out, 0, (size_t)out_size * 4, stream);

    k_init_h<<<(Nn * 64 + 255) / 256, 256, 0, stream>>>(h, hbm, z, emb);
    hipMemcpyAsync(xp, pos, (size_t)Nn * 3 * 4, hipMemcpyDeviceToDevice, stream);
    k_pack<<<(4 * 8192 + 4 * 4096 + 255) / 256, 256, 0, stream>>>(eW1, eW2, pw1, pw2);
    k_hist<<<(Ee + 255) / 256, 256, 0, stream>>>(ei0, deg);
    k_scan<<<1, 1024, 0, stream>>>(deg, rp);
    k_scatter<<<(Ee + 255) / 256, 256, 0, stream>>>(ei0, ei1, rp, cur, rows_s, cols_s);

    for (int l = 0; l < 4; ++l) {
        hipMemsetAsync(magg, 0, (size_t)Nn * 64 * 4, stream);
        hipMemsetAsync(xacc, 0, (size_t)Nn * 3 * 4, stream);
        k_edge<<<1024, 256, 0, stream>>>(rows_s, cols_s, hbm, xp,
                                         pw1 + (size_t)l * 8192, pw2 + (size_t)l * 4096,
                                         eW1 + (size_t)l * 129 * 64,
                                         eb1 + l * 64, eb2 + l * 64,
                                         cW + l * 64, cb + l, magg, xacc);
        k_node<<<(Nn + 63) / 64, 256, 0, stream>>>(magg, xacc,
                                                   nW1 + (size_t)l * 8192, nb1 + l * 64,
                                                   nW2 + (size_t)l * 4096, nb2 + l * 64,
                                                   h, hbm, xp);
    }
    k_q<<<(Nn + 63) / 64, 256, 0, stream>>>(h, qW1, qb1, qW2, qb2, qv);
    k_batch<<<(Nn + 255) / 256, 256, 0, stream>>>(batch, xp, cnt, xs);
    k_mu<<<(Nn + 255) / 256, 256, 0, stream>>>(batch, xp, qv, cnt, xs, (float*)d_out);
}

// Round 4
// 1753.972 us; speedup vs baseline: 2.2908x; 1.0286x over previous
//
#include <hip/hip_runtime.h>
#include <math.h>

#define Nn 50000
#define Ee 1600000
#define Bb 512
#define TE 64

typedef __bf16 bf16;
typedef __bf16 bf16x8 __attribute__((ext_vector_type(8)));
typedef __bf16 bf16x4 __attribute__((ext_vector_type(4)));
typedef float f32x4 __attribute__((ext_vector_type(4)));

__device__ __forceinline__ float silu_f(float v) {
    return v * __builtin_amdgcn_rcpf(1.f + __expf(-v));
}
__device__ __forceinline__ float tanh_f(float x) {
    float e = __expf(2.f * x);
    return 1.f - 2.f * __builtin_amdgcn_rcpf(e + 1.f);
}
__device__ __forceinline__ int pack2bf(float a, float b) {
    unsigned short ua = __builtin_bit_cast(unsigned short, (bf16)a);
    unsigned short ub = __builtin_bit_cast(unsigned short, (bf16)b);
    return (int)ua | ((int)ub << 16);
}

// ---------------- init: h = emb[z] (fp32 + bf16 mirror) ----------------
__global__ void k_init_h(float* __restrict__ h, bf16* __restrict__ hb,
                         const int* __restrict__ z, const float* __restrict__ emb) {
    int i = blockIdx.x * blockDim.x + threadIdx.x;
    if (i < Nn * 64) {
        int n = i >> 6, f = i & 63;
        float v = emb[z[n] * 64 + f];
        h[i] = v;
        hb[i] = (bf16)v;
    }
}

// ---------------- weight packing into MFMA A-fragment order ----------------
__global__ void k_pack(const float* __restrict__ eW1, const float* __restrict__ eW2,
                       bf16* __restrict__ pw1, bf16* __restrict__ pw2) {
    int tid = blockIdx.x * blockDim.x + threadIdx.x;
    if (tid < 4 * 8192) {
        int ll = tid >> 13, rem = tid & 8191;
        int j = rem & 7, lane = (rem >> 3) & 63, gT = rem >> 9;
        int kc = gT >> 2, T = gT & 3;
        int k = kc * 32 + (lane >> 4) * 8 + j;
        int n = T * 16 + (lane & 15);
        pw1[tid] = (bf16)eW1[(size_t)ll * 129 * 64 + k * 64 + n];
    } else if (tid < 4 * 8192 + 4 * 4096) {
        int idx = tid - 4 * 8192;
        int ll = idx >> 12, rem = idx & 4095;
        int j = rem & 7, lane = (rem >> 3) & 63, gT = rem >> 9;
        int kc = gT >> 2, T = gT & 3;
        int k = kc * 32 + (lane >> 4) * 8 + j;
        int n = T * 16 + (lane & 15);
        pw2[idx] = (bf16)eW2[(size_t)ll * 4096 + k * 64 + n];
    }
}

// ---------------- CSR build ----------------
__global__ void k_hist(const int* __restrict__ rows, int* __restrict__ deg) {
    int e = blockIdx.x * blockDim.x + threadIdx.x;
    if (e < Ee) atomicAdd(&deg[rows[e]], 1);
}

// two-level scan: per-thread serial chunk + one 1024-wide LDS scan
__global__ void k_scan(const int* __restrict__ deg, int* __restrict__ rp) {
    __shared__ int tot[1024];
    const int t = threadIdx.x;
    const int C = (Nn + 1023) / 1024;  // 49
    const int b = t * C;
    int s = 0;
    for (int i = 0; i < C; ++i) {
        int idx = b + i;
        if (idx < Nn) s += deg[idx];
    }
    tot[t] = s;
    __syncthreads();
    for (int off = 1; off < 1024; off <<= 1) {
        int u = (t >= off) ? tot[t - off] : 0;
        __syncthreads();
        tot[t] += u;
        __syncthreads();
    }
    int run = tot[t] - s;  // exclusive prefix of this chunk
    for (int i = 0; i < C; ++i) {
        int idx = b + i;
        if (idx < Nn) {
            rp[idx] = run;
            run += deg[idx];
        }
    }
    if (t == 1023) rp[Nn] = run;
}

__global__ void k_scatter(const int* __restrict__ rows, const int* __restrict__ cols,
                          const int* __restrict__ rp, int* __restrict__ cur,
                          int* __restrict__ rows_s, int* __restrict__ cols_s) {
    int e = blockIdx.x * blockDim.x + threadIdx.x;
    if (e < Ee) {
        int r = rows[e];
        int p = atomicAdd(&cur[r], 1);
        int o = rp[r] + p;
        rows_s[o] = r;
        cols_s[o] = cols[e];
    }
}

// ---------------- edge kernel (MFMA, per layer) ----------------
__global__ __launch_bounds__(256, 3) void k_edge(
    const int* __restrict__ rows_s, const int* __restrict__ cols_s,
    const bf16* __restrict__ hb, const float* __restrict__ x,
    const bf16* __restrict__ pw1l, const bf16* __restrict__ pw2l,
    const float* __restrict__ w1f32,
    const float* __restrict__ b1v, const float* __restrict__ b2v,
    const float* __restrict__ cwv, const float* __restrict__ cbv,
    float* __restrict__ m_agg, float* __restrict__ x_acc) {
    __shared__ __align__(16) bf16 hcatB[16 * 64 * 8];  // [kblock][edge][8]
    __shared__ float mE[64 * 65];                      // [n][e], stride 65
    __shared__ float relsm[64 * 4];
    __shared__ float dist2s[64];
    __shared__ float coefs[64];
    __shared__ int srow[64];
    __shared__ int segs[65];
    __shared__ int segr[64];
    __shared__ int nseg_s;
    __shared__ __align__(16) float b1s[64], w128s[64], b2s[64], cws[64];

    const int t = threadIdx.x;
    const int l = t & 63;
    const int w = t >> 6;
    const int q = l >> 4;
    const int nl = l & 15;

    // weight fragments (constant over tiles)
    bf16x8 w1f[4][4];
#pragma unroll
    for (int kc = 0; kc < 4; ++kc)
#pragma unroll
        for (int T = 0; T < 4; ++T)
            w1f[kc][T] = *(const bf16x8*)(pw1l + (((kc * 4 + T) * 64 + l) << 3));
    bf16x8 w2f[2][4];
#pragma unroll
    for (int c = 0; c < 2; ++c)
#pragma unroll
        for (int T = 0; T < 4; ++T)
            w2f[c][T] = *(const bf16x8*)(pw2l + (((c * 4 + T) * 64 + l) << 3));
    if (t < 64) {
        b1s[t] = b1v[t];
        w128s[t] = w1f32[128 * 64 + t];
        b2s[t] = b2v[t];
        cws[t] = cwv[t];
    }
    const float cb0 = cbv[0];
    const int qh = q >> 1;
    const int qb = 2 * (q & 1);
    const int fq = 4 * q;

    for (int tile = blockIdx.x; tile < Ee / TE; tile += gridDim.x) {
        const int base = tile * TE;
        __syncthreads();  // protect LDS reuse; also covers table init on iter 0

        if (t < TE) {
            int r = rows_s[base + t], c = cols_s[base + t];
            srow[t] = r;
            float rx = x[r * 3 + 0] - x[c * 3 + 0];
            float ry = x[r * 3 + 1] - x[c * 3 + 1];
            float rz = x[r * 3 + 2] - x[c * 3 + 2];
            relsm[t * 4 + 0] = rx;
            relsm[t * 4 + 1] = ry;
            relsm[t * 4 + 2] = rz;
            dist2s[t] = fmaf(rx, rx, fmaf(ry, ry, rz * rz));
        }
        {
            int ge = t >> 2, part = t & 3;
            int r = rows_s[base + ge], c = cols_s[base + ge];
            const bf16* hr = hb + ((size_t)r << 6) + part * 16;
            const bf16* hc = hb + ((size_t)c << 6) + part * 16;
            *(bf16x8*)&hcatB[(((part * 2 + 0) * 64) + ge) << 3] = *(const bf16x8*)(hr);
            *(bf16x8*)&hcatB[(((part * 2 + 1) * 64) + ge) << 3] = *(const bf16x8*)(hr + 8);
            *(bf16x8*)&hcatB[(((8 + part * 2 + 0) * 64) + ge) << 3] = *(const bf16x8*)(hc);
            *(bf16x8*)&hcatB[(((8 + part * 2 + 1) * 64) + ge) << 3] = *(const bf16x8*)(hc + 8);
        }
        __syncthreads();

        if (t < TE) {
            bool isst = (t == 0) || (srow[t] != srow[t - 1]);
            unsigned long long mask = __ballot(isst);
            if (isst) {
                int si = __popcll(mask & ((1ull << t) - 1ull));
                segs[si] = t;
                segr[si] = srow[t];
            }
            if (t == 0) {
                int ns = __popcll(mask);
                nseg_s = ns;
                segs[ns] = TE;
            }
        }

        // GEMM1: 16 MFMAs
        f32x4 a1[4];
#pragma unroll
        for (int T = 0; T < 4; ++T) a1[T] = (f32x4){0.f, 0.f, 0.f, 0.f};
#pragma unroll
        for (int kc = 0; kc < 4; ++kc) {
            bf16x8 bfrag = *(const bf16x8*)&hcatB[(((kc * 4 + q) * 64) + w * 16 + nl) << 3];
#pragma unroll
            for (int T = 0; T < 4; ++T)
                a1[T] = __builtin_amdgcn_mfma_f32_16x16x32_bf16(w1f[kc][T], bfrag, a1[T], 0, 0, 0);
        }
        // epilogue1: bias + fp32 dist2 rank-1 + silu, pack bf16 pairs
        float d2 = dist2s[w * 16 + nl];
        int pk[4][2];
#pragma unroll
        for (int T = 0; T < 4; ++T) {
            const float4 bq = *(const float4*)&b1s[T * 16 + fq];
            const float4 wq = *(const float4*)&w128s[T * 16 + fq];
            float h0 = silu_f(a1[T][0] + bq.x + wq.x * d2);
            float h1 = silu_f(a1[T][1] + bq.y + wq.y * d2);
            float h2 = silu_f(a1[T][2] + bq.z + wq.z * d2);
            float h3 = silu_f(a1[T][3] + bq.w + wq.w * d2);
            pk[T][0] = pack2bf(h0, h1);
            pk[T][1] = pack2bf(h2, h3);
        }
        // GEMM2: register-shuffle B-frags, 8 MFMAs
        f32x4 a2[4];
#pragma unroll
        for (int T = 0; T < 4; ++T) a2[T] = (f32x4){0.f, 0.f, 0.f, 0.f};
#pragma unroll
        for (int c = 0; c < 2; ++c) {
            union { int i[4]; bf16x8 v; } bu;
#pragma unroll
            for (int d = 0; d < 4; ++d) {
                int src = (qb + (d >> 1)) * 16 + nl;
                int t0 = __shfl(pk[2 * c][d & 1], src);
                int t1 = __shfl(pk[2 * c + 1][d & 1], src);
                bu.i[d] = qh ? t1 : t0;
            }
#pragma unroll
            for (int T = 0; T < 4; ++T)
                a2[T] = __builtin_amdgcn_mfma_f32_16x16x32_bf16(w2f[c][T], bu.v, a2[T], 0, 0, 0);
        }
        // epilogue2: bias + silu -> mE; coef dot in fp32
        float pc = 0.f;
#pragma unroll
        for (int T = 0; T < 4; ++T) {
            const float4 bq = *(const float4*)&b2s[T * 16 + fq];
            const float4 cq = *(const float4*)&cws[T * 16 + fq];
            float m0 = silu_f(a2[T][0] + bq.x);
            float m1 = silu_f(a2[T][1] + bq.y);
            float m2 = silu_f(a2[T][2] + bq.z);
            float m3 = silu_f(a2[T][3] + bq.w);
            mE[(T * 16 + fq + 0) * 65 + w * 16 + nl] = m0;
            mE[(T * 16 + fq + 1) * 65 + w * 16 + nl] = m1;
            mE[(T * 16 + fq + 2) * 65 + w * 16 + nl] = m2;
            mE[(T * 16 + fq + 3) * 65 + w * 16 + nl] = m3;
            pc += m0 * cq.x + m1 * cq.y + m2 * cq.z + m3 * cq.w;
        }
        pc += __shfl_xor(pc, 16);
        pc += __shfl_xor(pc, 32);
        if (q == 0) coefs[w * 16 + nl] = tanh_f(pc + cb0);
        __syncthreads();

        // segmented aggregation
        {
            int g = t >> 6, n = t & 63;
            int ns = nseg_s;
            for (int s = g; s < ns; s += 4) {
                int st = segs[s], en = segs[s + 1];
                float sum = 0.f;
                for (int e = st; e < en; ++e) sum += mE[n * 65 + e];
                atomicAdd(m_agg + (size_t)segr[s] * 64 + n, sum);
            }
            if (t < 3 * ns) {
                int s = t / 3, cc = t - s * 3;
                int st = segs[s], en = segs[s + 1];
                float sum = 0.f;
                for (int e = st; e < en; ++e) sum += relsm[e * 4 + cc] * coefs[e];
                atomicAdd(x_acc + (size_t)segr[s] * 3 + cc, sum);
            }
        }
    }
}

// ---------------- node kernel (fp32, per layer) ----------------
#define FMA16(ACC, EV, WV)                                         \
    ACC[0][0] = fmaf(EV.x, WV.x, ACC[0][0]);                       \
    ACC[0][1] = fmaf(EV.x, WV.y, ACC[0][1]);                       \
    ACC[0][2] = fmaf(EV.x, WV.z, ACC[0][2]);                       \
    ACC[0][3] = fmaf(EV.x, WV.w, ACC[0][3]);                       \
    ACC[1][0] = fmaf(EV.y, WV.x, ACC[1][0]);                       \
    ACC[1][1] = fmaf(EV.y, WV.y, ACC[1][1]);                       \
    ACC[1][2] = fmaf(EV.y, WV.z, ACC[1][2]);                       \
    ACC[1][3] = fmaf(EV.y, WV.w, ACC[1][3]);                       \
    ACC[2][0] = fmaf(EV.z, WV.x, ACC[2][0]);                       \
    ACC[2][1] = fmaf(EV.z, WV.y, ACC[2][1]);                       \
    ACC[2][2] = fmaf(EV.z, WV.z, ACC[2][2]);                       \
    ACC[2][3] = fmaf(EV.z, WV.w, ACC[2][3]);                       \
    ACC[3][0] = fmaf(EV.w, WV.x, ACC[3][0]);                       \
    ACC[3][1] = fmaf(EV.w, WV.y, ACC[3][1]);                       \
    ACC[3][2] = fmaf(EV.w, WV.z, ACC[3][2]);                       \
    ACC[3][3] = fmaf(EV.w, WV.w, ACC[3][3]);

__global__ __launch_bounds__(256) void k_node(
    const float* __restrict__ m_agg, const float* __restrict__ x_acc,
    const float* __restrict__ w1, const float* __restrict__ b1v,
    const float* __restrict__ w2, const float* __restrict__ b2v,
    float* __restrict__ h, bf16* __restrict__ hb, float* __restrict__ x) {
    __shared__ float inT[128 * 64];
    __shared__ float h1T[64 * 64];
    __shared__ float sb1[64], sb2[64];
    const int t = threadIdx.x;
    const int tx = t & 15, ty = t >> 4;
    const int f0 = tx * 4, e0 = ty * 4;
    if (t < 64) { sb1[t] = b1v[t]; sb2[t] = b2v[t]; }
    const int base = blockIdx.x * 64;
    {
        int nl = t >> 2, part = t & 3;
        int n = base + nl;
        if (n < Nn) {
            const float4* hr = (const float4*)(h + (size_t)n * 64 + part * 16);
            const float4* mr = (const float4*)(m_agg + (size_t)n * 64 + part * 16);
#pragma unroll
            for (int j = 0; j < 4; ++j) {
                float4 v = hr[j];
                int f = part * 16 + j * 4;
                inT[(f + 0) * 64 + nl] = v.x;
                inT[(f + 1) * 64 + nl] = v.y;
                inT[(f + 2) * 64 + nl] = v.z;
                inT[(f + 3) * 64 + nl] = v.w;
            }
#pragma unroll
            for (int j = 0; j < 4; ++j) {
                float4 v = mr[j];
                int f = 64 + part * 16 + j * 4;
                inT[(f + 0) * 64 + nl] = v.x;
                inT[(f + 1) * 64 + nl] = v.y;
                inT[(f + 2) * 64 + nl] = v.z;
                inT[(f + 3) * 64 + nl] = v.w;
            }
        } else {
#pragma unroll
            for (int j = 0; j < 4; ++j) {
                int f = part * 16 + j * 4;
#pragma unroll
                for (int i = 0; i < 4; ++i) {
                    inT[(f + i) * 64 + nl] = 0.f;
                    inT[(64 + f + i) * 64 + nl] = 0.f;
                }
            }
        }
    }
    __syncthreads();
    float acc[4][4];
#pragma unroll
    for (int i = 0; i < 4; ++i)
#pragma unroll
        for (int j = 0; j < 4; ++j) acc[i][j] = sb1[f0 + j];
#pragma unroll 4
    for (int k = 0; k < 128; ++k) {
        const float4 wv = *(const float4*)(w1 + (k << 6) + f0);
        const float4 ev = *(const float4*)(inT + (k << 6) + e0);
        FMA16(acc, ev, wv)
    }
#pragma unroll
    for (int j = 0; j < 4; ++j) {
        float4 sv;
        sv.x = silu_f(acc[0][j]);
        sv.y = silu_f(acc[1][j]);
        sv.z = silu_f(acc[2][j]);
        sv.w = silu_f(acc[3][j]);
        *(float4*)(h1T + (f0 + j) * 64 + e0) = sv;
    }
    __syncthreads();
    float a2[4][4];
#pragma unroll
    for (int i = 0; i < 4; ++i)
#pragma unroll
        for (int j = 0; j < 4; ++j) a2[i][j] = sb2[f0 + j];
#pragma unroll 4
    for (int k = 0; k < 64; ++k) {
        const float4 wv = *(const float4*)(w2 + (k << 6) + f0);
        const float4 ev = *(const float4*)(h1T + (k << 6) + e0);
        FMA16(a2, ev, wv)
    }
#pragma unroll
    for (int i = 0; i < 4; ++i) {
        int n = base + e0 + i;
        if (n < Nn) {
            float4* hp = (float4*)(h + (size_t)n * 64 + f0);
            float4 old = *hp;
            old.x += a2[i][0];
            old.y += a2[i][1];
            old.z += a2[i][2];
            old.w += a2[i][3];
            *hp = old;
            bf16x4 hv = {(bf16)old.x, (bf16)old.y, (bf16)old.z, (bf16)old.w};
            *(bf16x4*)(hb + (size_t)n * 64 + f0) = hv;
        }
    }
    if (t < 64) {
        int n = base + t;
        if (n < Nn) {
#pragma unroll
            for (int c = 0; c < 3; ++c) x[n * 3 + c] += x_acc[n * 3 + c];
        }
    }
}

// ---------------- readout q ----------------
__global__ __launch_bounds__(256) void k_q(
    const float* __restrict__ h,
    const float* __restrict__ w1, const float* __restrict__ b1v,
    const float* __restrict__ w2, const float* __restrict__ b2v,
    float* __restrict__ q) {
    __shared__ float hT[64 * 64];
    __shared__ float sb1[64], sw2[64];
    const int t = threadIdx.x;
    const int tx = t & 15, ty = t >> 4;
    const int f0 = tx * 4, e0 = ty * 4;
    if (t < 64) { sb1[t] = b1v[t]; sw2[t] = w2[t]; }
    const float qb2 = b2v[0];
    const int base = blockIdx.x * 64;
    {
        int nl = t >> 2, part = t & 3;
        int n = base + nl;
        if (n < Nn) {
            const float4* hr = (const float4*)(h + (size_t)n * 64 + part * 16);
#pragma unroll
            for (int j = 0; j < 4; ++j) {
                float4 v = hr[j];
                int f = part * 16 + j * 4;
                hT[(f + 0) * 64 + nl] = v.x;
                hT[(f + 1) * 64 + nl] = v.y;
                hT[(f + 2) * 64 + nl] = v.z;
                hT[(f + 3) * 64 + nl] = v.w;
            }
        } else {
#pragma unroll
            for (int j = 0; j < 4; ++j) {
                int f = part * 16 + j * 4;
#pragma unroll
                for (int i = 0; i < 4; ++i) hT[(f + i) * 64 + nl] = 0.f;
            }
        }
    }
    __syncthreads();
    float acc[4][4];
#pragma unroll
    for (int i = 0; i < 4; ++i)
#pragma unroll
        for (int j = 0; j < 4; ++j) acc[i][j] = sb1[f0 + j];
#pragma unroll 4
    for (int k = 0; k < 64; ++k) {
        const float4 wv = *(const float4*)(w1 + (k << 6) + f0);
        const float4 ev = *(const float4*)(hT + (k << 6) + e0);
        FMA16(acc, ev, wv)
    }
    float p[4];
#pragma unroll
    for (int i = 0; i < 4; ++i) {
        p[i] = fmaf(silu_f(acc[i][0]), sw2[f0 + 0],
               fmaf(silu_f(acc[i][1]), sw2[f0 + 1],
               fmaf(silu_f(acc[i][2]), sw2[f0 + 2],
                    silu_f(acc[i][3]) * sw2[f0 + 3])));
    }
#pragma unroll
    for (int off = 1; off < 16; off <<= 1) {
#pragma unroll
        for (int i = 0; i < 4; ++i) p[i] += __shfl_xor(p[i], off);
    }
    if (tx == 0) {
#pragma unroll
        for (int i = 0; i < 4; ++i) {
            int n = base + e0 + i;
            if (n < Nn) q[n] = p[i] + qb2;
        }
    }
}

// ---------------- batch stats & dipole ----------------
__global__ void k_batch(const int* __restrict__ batch, const float* __restrict__ x,
                        float* __restrict__ cnt, float* __restrict__ xs) {
    int n = blockIdx.x * blockDim.x + threadIdx.x;
    if (n < Nn) {
        int b = batch[n];
        atomicAdd(&cnt[b], 1.f);
        atomicAdd(&xs[b * 3 + 0], x[n * 3 + 0]);
        atomicAdd(&xs[b * 3 + 1], x[n * 3 + 1]);
        atomicAdd(&xs[b * 3 + 2], x[n * 3 + 2]);
    }
}

__global__ void k_mu(const int* __restrict__ batch, const float* __restrict__ x,
                     const float* __restrict__ q, const float* __restrict__ cnt,
                     const float* __restrict__ xs, float* __restrict__ out) {
    int n = blockIdx.x * blockDim.x + threadIdx.x;
    if (n < Nn) {
        int b = batch[n];
        float cc = fmaxf(cnt[b], 1.f);
        float qn = q[n];
#pragma unroll
        for (int c = 0; c < 3; ++c) {
            float xr = x[n * 3 + c] - xs[b * 3 + c] / cc;
            atomicAdd(&out[b * 3 + c], qn * xr);
        }
    }
}

// ---------------- launch ----------------
extern "C" void kernel_launch(void* const* d_in, const int* in_sizes, int n_in,
                              void* d_out, int out_size, void* d_ws, size_t ws_size,
                              hipStream_t stream) {
    const int* z = (const int*)d_in[0];
    const float* pos = (const float*)d_in[1];
    const int* ei0 = (const int*)d_in[2];
    const int* ei1 = ei0 + Ee;
    const int* batch = (const int*)d_in[3];
    const float* emb = (const float*)d_in[4];
    const float* eW1 = (const float*)d_in[5];
    const float* eb1 = (const float*)d_in[6];
    const float* eW2 = (const float*)d_in[7];
    const float* eb2 = (const float*)d_in[8];
    const float* cW = (const float*)d_in[9];
    const float* cb = (const float*)d_in[10];
    const float* nW1 = (const float*)d_in[11];
    const float* nb1 = (const float*)d_in[12];
    const float* nW2 = (const float*)d_in[13];
    const float* nb2 = (const float*)d_in[14];
    const float* qW1 = (const float*)d_in[15];
    const float* qb1 = (const float*)d_in[16];
    const float* qW2 = (const float*)d_in[17];
    const float* qb2 = (const float*)d_in[18];

    char* ws = (char*)d_ws;
    size_t o = 0;
    auto alloc = [&](size_t bytes) {
        size_t r = o;
        o = (o + bytes + 255) & ~(size_t)255;
        return r;
    };
    float* h = (float*)(ws + alloc((size_t)Nn * 64 * 4));
    float* xp = (float*)(ws + alloc((size_t)Nn * 3 * 4));
    float* magg = (float*)(ws + alloc((size_t)Nn * 64 * 4));
    float* xacc = (float*)(ws + alloc((size_t)Nn * 3 * 4));
    float* qv = (float*)(ws + alloc((size_t)Nn * 4));
    int* deg = (int*)(ws + alloc((size_t)Nn * 4));
    int* rp = (int*)(ws + alloc((size_t)(Nn + 1) * 4));
    int* cur = (int*)(ws + alloc((size_t)Nn * 4));
    int* rows_s = (int*)(ws + alloc((size_t)Ee * 4));
    int* cols_s = (int*)(ws + alloc((size_t)Ee * 4));
    float* cnt = (float*)(ws + alloc((size_t)Bb * 4));
    float* xs = (float*)(ws + alloc((size_t)Bb * 3 * 4));
    bf16* hbm = (bf16*)(ws + alloc((size_t)Nn * 64 * 2));
    bf16* pw1 = (bf16*)(ws + alloc((size_t)4 * 8192 * 2));
    bf16* pw2 = (bf16*)(ws + alloc((size_t)4 * 4096 * 2));

    hipMemsetAsync(deg, 0, (size_t)Nn * 4, stream);
    hipMemsetAsync(cur, 0, (size_t)Nn * 4, stream);
    hipMemsetAsync(cnt, 0, (size_t)Bb * 4, stream);
    hipMemsetAsync(xs, 0, (size_t)Bb * 3 * 4, stream);
    hipMemsetAsync(d_out, 0, (size_t)out_size * 4, stream);

    k_init_h<<<(Nn * 64 + 255) / 256, 256, 0, stream>>>(h, hbm, z, emb);
    hipMemcpyAsync(xp, pos, (size_t)Nn * 3 * 4, hipMemcpyDeviceToDevice, stream);
    k_pack<<<(4 * 8192 + 4 * 4096 + 255) / 256, 256, 0, stream>>>(eW1, eW2, pw1, pw2);
    k_hist<<<(Ee + 255) / 256, 256, 0, stream>>>(ei0, deg);
    k_scan<<<1, 1024, 0, stream>>>(deg, rp);
    k_scatter<<<(Ee + 255) / 256, 256, 0, stream>>>(ei0, ei1, rp, cur, rows_s, cols_s);

    for (int l = 0; l < 4; ++l) {
        hipMemsetAsync(magg, 0, (size_t)Nn * 64 * 4, stream);
        hipMemsetAsync(xacc, 0, (size_t)Nn * 3 * 4, stream);
        k_edge<<<1024, 256, 0, stream>>>(rows_s, cols_s, hbm, xp,
                                         pw1 + (size_t)l * 8192, pw2 + (size_t)l * 4096,
                                         eW1 + (size_t)l * 129 * 64,
                                         eb1 + l * 64, eb2 + l * 64,
                                         cW + l * 64, cb + l, magg, xacc);
        k_node<<<(Nn + 63) / 64, 256, 0, stream>>>(magg, xacc,
                                                   nW1 + (size_t)l * 8192, nb1 + l * 64,
                                                   nW2 + (size_t)l * 4096, nb2 + l * 64,
                                                   h, hbm, xp);
    }
    k_q<<<(Nn + 63) / 64, 256, 0, stream>>>(h, qW1, qb1, qW2, qb2, qv);
    k_batch<<<(Nn + 255) / 256, 256, 0, stream>>>(batch, xp, cnt, xs);
    k_mu<<<(Nn + 255) / 256, 256, 0, stream>>>(batch, xp, qv, cnt, xs, (float*)d_out);
}